// Round 4
// baseline (3504.964 us; speedup 1.0000x reference)
//
#include <hip/hip_runtime.h>
#include <hip/hip_bf16.h>
#include <math.h>

#define NND 100000   // nodes
#define NED 200000   // edges
#define MROWS 100096 // NND padded to 128-multiple (782 M-tiles)
// MEM=172, TD=100, K=10, MSG=616, 3*MEM=516

using bf16 = __hip_bfloat16;
using short8 = __attribute__((ext_vector_type(8))) short;
using short4v = __attribute__((ext_vector_type(4))) short;
using f32x4  = __attribute__((ext_vector_type(4))) float;

typedef __attribute__((address_space(3))) void lds_t;
typedef __attribute__((address_space(1))) const void gv_t;
__device__ __forceinline__ void gl16(const void* g, void* l) {
  __builtin_amdgcn_global_load_lds((gv_t*)g, (lds_t*)l, 16, 0, 0);
}

__device__ __forceinline__ float bfs2f(short s) {
  union { unsigned u; float f; } v; v.u = ((unsigned)(unsigned short)s) << 16; return v.f;
}
__device__ __forceinline__ short f2bfs(float f) {
  bf16 b = __float2bfloat16(f);
  union { bf16 b; short s; } u; u.b = b; return u.s;
}

// ---- native-transcendental helpers (v_cos/v_exp/v_rcp; quarter-rate HW pipes)
#define INV2PI 0.15915494309189533577f

__device__ __forceinline__ float cos_rev(float r) {
  r = r - floorf(r);
  return __builtin_amdgcn_cosf(r);
}
__device__ __forceinline__ float fast_exp(float x) { return __expf(x); }
__device__ __forceinline__ float fast_rcp(float x) { return __builtin_amdgcn_rcpf(x); }
__device__ __forceinline__ float fast_sigmoid(float x) {
  return __builtin_amdgcn_rcpf(1.f + __expf(-x));
}
__device__ __forceinline__ float fast_tanh(float x) {
  float e = __expf(2.f * fabsf(x));
  float t = 1.f - 2.f * __builtin_amdgcn_rcpf(e + 1.f);
  return copysignf(t, x);
}

// ---------------------------------------------------------------- small kernels

__global__ void init_k(int* lastpos, float* relu_sum, const float* __restrict__ tw,
                       const float* __restrict__ tb, float* twp, float* tbp) {
  int i = blockIdx.x * 256 + threadIdx.x;
  if (i < NND) lastpos[i] = -1;
  if (i < 172) relu_sum[i] = 0.f;
  if (i < 128) {  // prescaled (revolutions) zero-padded time-encoding coeffs
    twp[i] = (i < 100) ? tw[i] * INV2PI : 0.f;
    tbp[i] = (i < 100) ? tb[i] * INV2PI : 0.f;
  }
}

__global__ void scatter_k(const int* __restrict__ src, const int* __restrict__ dst,
                          int* lastpos) {
  int e = blockIdx.x * 256 + threadIdx.x;
  if (e < NED) {
    atomicMax(&lastpos[src[e]], e);
    atomicMax(&lastpos[dst[e]], NED + e);
  }
}

__global__ void meta_k(const int* __restrict__ lastpos,
                       const int* __restrict__ src, const int* __restrict__ dst,
                       const float* __restrict__ ts, const float* __restrict__ last_update,
                       int* other, int* edge, float* dtv, int* hasm) {
  int n = blockIdx.x * 256 + threadIdx.x;
  if (n >= NND) return;
  int p = lastpos[n];
  int oth = n, e = 0, hm = 0;
  float d = 0.f;
  if (p >= 0) {
    hm = 1;
    if (p >= NED) { e = p - NED; oth = src[e]; }   // node was destination
    else          { e = p;       oth = dst[e]; }   // node was source
    d = ts[e] - last_update[n];
  }
  other[n] = oth; edge[n] = e; dtv[n] = d; hasm[n] = hm;
}

__global__ void qbias_k(const float* __restrict__ tb, const float* __restrict__ Wq,
                        float* qbias) {
  int o = threadIdx.x;
  if (o < 172) {
    float s = 0.f;
    for (int d = 0; d < 100; d++) s += cosf(tb[d]) * Wq[(172 + d) * 172 + o];
    qbias[o] = s;
  }
}

// bias for the 716 proj cols: [qbias | 0(344) | qk2-const]
__global__ void bias716_k(const float* __restrict__ qbias, const float* __restrict__ Wk,
                          float* bias) {
  int o = blockIdx.x * 256 + threadIdx.x;
  if (o >= 716) return;
  float v = 0.f;
  if (o < 172) v = qbias[o];
  else if (o >= 516) {
    int p = o - 516, hh = p / 100, d = p - hh * 100;
    const float* qb  = qbias + hh * 86;
    const float* wk2 = Wk + (172 + d) * 172 + hh * 86;
    float s = 0.f;
    for (int cc = 0; cc < 86; cc++) s = fmaf(qb[cc], wk2[cc], s);
    v = s;
  }
  bias[o] = v;
}

// f32 -> bf16 weight convert with zero padding
__global__ void cvtW_k(const float* __restrict__ src, bf16* __restrict__ dst,
                       int R, int S, int r, int s) {
  int i = blockIdx.x * 256 + threadIdx.x;
  if (i >= R * S) return;
  int rr = i / S, cc = i - rr * S;
  float v = (rr < r && cc < s) ? src[(size_t)rr * s + cc] : 0.f;
  dst[i] = __float2bfloat16(v);
}

// packed proj weight, transposed bf16: [768 rows x 192] = [Wq | Wk | Wv | Wqk2]^T
__global__ void packBT_k(const float* __restrict__ Wq, const float* __restrict__ Wk,
                         const float* __restrict__ Wv, bf16* __restrict__ dst) {
  int i = blockIdx.x * 256 + threadIdx.x;
  if (i >= 768 * 192) return;
  int o = i / 192, c = i - o * 192;
  float v = 0.f;
  if (o < 716 && c < 172) {
    if (o < 172)      v = Wq[c * 172 + o];
    else if (o < 344) v = Wk[c * 172 + (o - 172)];
    else if (o < 516) v = Wv[c * 172 + (o - 344)];
    else {
      int p = o - 516, hh = p / 100, d = p - hh * 100;
      const float* wq  = Wq + c * 172 + hh * 86;
      const float* wk2 = Wk + (172 + d) * 172 + hh * 86;
      float s = 0.f;
      for (int cc = 0; cc < 86; cc++) s = fmaf(wq[cc], wk2[cc], s);
      v = s;
    }
  }
  dst[i] = __float2bfloat16(v);
}

// extended W1 weight, transposed bf16: [256 rows x 544]
__global__ void packW1x_k(const float* __restrict__ W1, const float* __restrict__ Wv,
                          bf16* __restrict__ dst) {
  int i = blockIdx.x * 256 + threadIdx.x;
  if (i >= 256 * 544) return;
  int o = i / 544, k = i - o * 544;
  float v = 0.f;
  if (o < 172) {
    if (k < 344) v = W1[(size_t)k * 172 + o];
    else {
      int p = k - 344, hh = p / 100, d = p - hh * 100;
      const float* wv2 = Wv + (size_t)(172 + d) * 172;
      float s = 0.f;
      for (int t = hh * 86; t < hh * 86 + 86; t++)
        s = fmaf(wv2[t], W1[(size_t)(172 + t) * 172 + o], s);
      v = s;
    }
  }
  dst[i] = __float2bfloat16(v);
}

// message matrix Mg [MROWS x 640] bf16; one thread = one short8 (8 cols)
__global__ void msg2_k(const float* __restrict__ mem, const float* __restrict__ ef,
                       const int* __restrict__ other, const int* __restrict__ edge,
                       const float* __restrict__ dtv, const float* __restrict__ twp,
                       const float* __restrict__ tbp, bf16* __restrict__ Mg) {
  int i = blockIdx.x * 256 + threadIdx.x;
  if (i >= MROWS * 80) return;
  int n = i / 80, c8 = i - n * 80;
  int c = c8 * 8;
  short8 st = {0, 0, 0, 0, 0, 0, 0, 0};
  if (n < NND && c < 616) {
    float v[8];
    if (c + 8 <= 172) {                       // memory[n]
      float4 a = *(const float4*)(mem + (size_t)n * 172 + c);
      float4 b = *(const float4*)(mem + (size_t)n * 172 + c + 4);
      v[0]=a.x; v[1]=a.y; v[2]=a.z; v[3]=a.w; v[4]=b.x; v[5]=b.y; v[6]=b.z; v[7]=b.w;
    } else if (c >= 176 && c + 8 <= 344) {    // memory[other]
      const float* src = mem + (size_t)other[n] * 172 + (c - 172);
      float4 a = *(const float4*)(src);
      float4 b = *(const float4*)(src + 4);
      v[0]=a.x; v[1]=a.y; v[2]=a.z; v[3]=a.w; v[4]=b.x; v[5]=b.y; v[6]=b.z; v[7]=b.w;
    } else if (c >= 344 && c + 8 <= 516) {    // edge features
      const float* src = ef + (size_t)edge[n] * 172 + (c - 344);
      float4 a = *(const float4*)(src);
      float4 b = *(const float4*)(src + 4);
      v[0]=a.x; v[1]=a.y; v[2]=a.z; v[3]=a.w; v[4]=b.x; v[5]=b.y; v[6]=b.z; v[7]=b.w;
    } else if (c >= 520) {                    // pure time-encoding
      float d0 = dtv[n];
      #pragma unroll
      for (int p = 0; p < 8; p++)
        v[p] = cos_rev(fmaf(d0, twp[c - 516 + p], tbp[c - 516 + p]));
    } else {                                  // boundary threads (c8==21, c8==64)
      float d0 = dtv[n];
      #pragma unroll
      for (int p = 0; p < 8; p++) {
        int col = c + p;
        float x;
        if (col < 172)      x = mem[(size_t)n * 172 + col];
        else if (col < 344) x = mem[(size_t)other[n] * 172 + (col - 172)];
        else if (col < 516) x = ef[(size_t)edge[n] * 172 + (col - 344)];
        else                x = cos_rev(fmaf(d0, twp[col - 516], tbp[col - 516]));
        v[p] = x;
      }
    }
    #pragma unroll
    for (int p = 0; p < 8; p++) st[p] = f2bfs(v[p]);
  }
  *(short8*)(Mg + (size_t)n * 640 + c) = st;
}

// memory f32 -> bf16 [MROWS x 192] zero-padded
__global__ void cvtmem_k(const float* __restrict__ mem, bf16* __restrict__ dst) {
  int i = blockIdx.x * 256 + threadIdx.x;
  if (i >= MROWS * 192) return;
  int n = i / 192, c = i - n * 192;
  float v = (n < NND && c < 172) ? mem[(size_t)n * 172 + c] : 0.f;
  dst[i] = __float2bfloat16(v);
}

// zero pad rows of haw (rows NND..MROWS-1, 544 cols)
__global__ void padrow_k(bf16* __restrict__ haw) {
  int i = blockIdx.x * 256 + threadIdx.x;
  if (i < (MROWS - NND) * 544) haw[(size_t)NND * 544 + i] = __float2bfloat16(0.f);
}

// GRU combine; one thread = 4 cols. Writes hB [MROWS x 192] and haw cols 0..171
__global__ void gru2_k(const bf16* __restrict__ gi, const bf16* __restrict__ gh,
                       const float* __restrict__ memory, const float* __restrict__ nf,
                       const int* __restrict__ hasm,
                       bf16* __restrict__ hB, bf16* __restrict__ haw) {
  int i = blockIdx.x * 256 + threadIdx.x;
  if (i >= MROWS * 48) return;
  int n = i / 48, c = (i - n * 48) * 4;
  short4v z4 = {0, 0, 0, 0};
  if (n >= NND || c >= 172) {
    *(short4v*)(hB + (size_t)n * 192 + c) = z4;
    return;
  }
  float4 mv = *(const float4*)(memory + (size_t)n * 172 + c);
  float hv[4] = {mv.x, mv.y, mv.z, mv.w};
  if (hasm[n]) {
    const bf16* gin = gi + (size_t)n * 516 + c;
    const bf16* ghn = gh + (size_t)n * 516 + c;
    short4v g0 = *(const short4v*)(gin);
    short4v g1 = *(const short4v*)(gin + 172);
    short4v g2 = *(const short4v*)(gin + 344);
    short4v h0 = *(const short4v*)(ghn);
    short4v h1 = *(const short4v*)(ghn + 172);
    short4v h2 = *(const short4v*)(ghn + 344);
    #pragma unroll
    for (int p = 0; p < 4; p++) {
      float r  = fast_sigmoid(bfs2f(g0[p]) + bfs2f(h0[p]));
      float zz = fast_sigmoid(bfs2f(g1[p]) + bfs2f(h1[p]));
      float nn = fast_tanh(bfs2f(g2[p]) + r * bfs2f(h2[p]));
      hv[p] = (1.f - zz) * nn + zz * hv[p];
    }
  }
  float4 nfv = *(const float4*)(nf + (size_t)n * 172 + c);
  float nfa[4] = {nfv.x, nfv.y, nfv.z, nfv.w};
  short4v hb;
  #pragma unroll
  for (int p = 0; p < 4; p++) hb[p] = f2bfs(hv[p] + nfa[p]);
  *(short4v*)(hB + (size_t)n * 192 + c) = hb;
  *(short4v*)(haw + (size_t)n * 544 + c) = hb;
}

// ---------------------------------------------------------------- bf16 MFMA GEMM
// C[M,O] = A[M,K] @ B^T + bias. 128x128 tile, BK=32, 4 waves.
// 2-phase double-buffered staging (T3-minimum): stage next K-tile BEFORE
// computing current; one __syncthreads() per iter doubles as vmcnt-drain+join.
// EPI 1: relu + column-sum (skip row 0) -> red.  EPI 2: bf16 store to Cb.
// EPI 3: proj split -> Cq bf16 [q | qk2 -> cols 172..371] stride CqS,
//        Cb bf16 [cols 172..515 -> 0..343, zeros to 344..511] stride CbS.

template<int EPI>
__global__ __launch_bounds__(256) void mgemm_k(
    const bf16* __restrict__ A, int AS, const bf16* __restrict__ B, int BS,
    const float* __restrict__ bias,
    bf16* __restrict__ Cq, int CqS, bf16* __restrict__ Cb, int CbS,
    float* __restrict__ red, int M, int O, int K) {
  __shared__ bf16 As[2][128 * 32];
  __shared__ bf16 Bs[2][128 * 32];
  const int tid = threadIdx.x, w = tid >> 6, lane = tid & 63;
  const int m0 = blockIdx.y * 128, o0 = blockIdx.x * 128;
  const int quad = lane >> 4, l16 = lane & 15;
  const int wm = (w & 1) * 64, wn = (w >> 1) * 64;
  const int wo = w * 1024;
  f32x4 acc[4][4] = {};
  const bf16* ga = A + (size_t)(m0 + w * 32 + (lane >> 2)) * AS + (lane & 3) * 8;
  const bf16* gb = B + (size_t)(o0 + w * 32 + (lane >> 2)) * BS + (lane & 3) * 8;
  // prologue: stage buffer 0
  gl16(ga, As[0] + wo);  gl16(ga + (size_t)16 * AS, As[0] + wo + 512);
  gl16(gb, Bs[0] + wo);  gl16(gb + (size_t)16 * BS, Bs[0] + wo + 512);
  ga += 32; gb += 32;
  __syncthreads();                       // vmcnt(0) drain + join
  const int nt = K >> 5;
  int cur = 0;
  for (int t = 0; t < nt; ++t) {
    if (t + 1 < nt) {                    // stage NEXT tile into other buffer
      gl16(ga, As[cur ^ 1] + wo);  gl16(ga + (size_t)16 * AS, As[cur ^ 1] + wo + 512);
      gl16(gb, Bs[cur ^ 1] + wo);  gl16(gb + (size_t)16 * BS, Bs[cur ^ 1] + wo + 512);
      ga += 32; gb += 32;
    }
    short8 af[4], bfm[4];
    #pragma unroll
    for (int i = 0; i < 4; i++)
      af[i] = *(const short8*)&As[cur][(wm + i * 16 + l16) * 32 + quad * 8];
    #pragma unroll
    for (int j = 0; j < 4; j++)
      bfm[j] = *(const short8*)&Bs[cur][(wn + j * 16 + l16) * 32 + quad * 8];
    #pragma unroll
    for (int i = 0; i < 4; i++)
      #pragma unroll
      for (int j = 0; j < 4; j++)
        acc[i][j] = __builtin_amdgcn_mfma_f32_16x16x32_bf16(af[i], bfm[j], acc[i][j], 0, 0, 0);
    __syncthreads();                     // drain next-stage + all waves done reading cur
    cur ^= 1;
  }
  if (EPI == 2) {
    #pragma unroll
    for (int i = 0; i < 4; i++)
      #pragma unroll
      for (int p = 0; p < 4; p++) {
        const int m = m0 + wm + i * 16 + quad * 4 + p;
        if (m < M) {
          #pragma unroll
          for (int j = 0; j < 4; j++) {
            const int o = o0 + wn + j * 16 + l16;
            if (o < O) Cb[(size_t)m * CbS + o] = __float2bfloat16(acc[i][j][p] + bias[o]);
          }
        }
      }
  } else if (EPI == 3) {
    #pragma unroll
    for (int i = 0; i < 4; i++)
      #pragma unroll
      for (int p = 0; p < 4; p++) {
        const int m = m0 + wm + i * 16 + quad * 4 + p;
        if (m < M) {
          #pragma unroll
          for (int j = 0; j < 4; j++) {
            const int o = o0 + wn + j * 16 + l16;
            if (o < O) {
              const float v = acc[i][j][p] + bias[o];
              if (o < 172)      Cq[(size_t)m * CqS + o] = __float2bfloat16(v);
              else if (o < 516) Cb[(size_t)m * CbS + (o - 172)] = __float2bfloat16(v);
              else {
                Cq[(size_t)m * CqS + (o - 344)] = __float2bfloat16(v);
                if (o < 684) Cb[(size_t)m * CbS + (o - 172)] = __float2bfloat16(0.f);
              }
            }
          }
        }
      }
  } else {  // EPI == 1: relu + colsum (rows 1..M-1)
    __shared__ float colsum[128];
    if (tid < 128) colsum[tid] = 0.f;
    __syncthreads();
    float part[4] = {0.f, 0.f, 0.f, 0.f};
    #pragma unroll
    for (int i = 0; i < 4; i++)
      #pragma unroll
      for (int p = 0; p < 4; p++) {
        const int m = m0 + wm + i * 16 + quad * 4 + p;
        const bool valid = (m < M) && (m != 0);
        if (valid) {
          #pragma unroll
          for (int j = 0; j < 4; j++) {
            const int o = o0 + wn + j * 16 + l16;
            if (o < O) part[j] += fmaxf(acc[i][j][p] + bias[o], 0.f);
          }
        }
      }
    #pragma unroll
    for (int j = 0; j < 4; j++) atomicAdd(&colsum[wn + j * 16 + l16], part[j]);
    __syncthreads();
    if (tid < 128) {
      const int o = o0 + tid;
      if (o < O) atomicAdd(&red[o], colsum[tid]);
    }
  }
}

// ---------------------------------------------------------------- attention v5
// Wave per node, branchless. Cq is bf16 (stride 384). VGPR-slim: kv is
// re-gathered in the agg phase (L2/L3-hot) and time encodings recomputed,
// so nothing bulky lives across the softmax -> target 8 waves/SIMD.
__global__ __launch_bounds__(256, 8) void attn5_k(
    const bf16* __restrict__ Cq, const bf16* __restrict__ kv,
    const float* __restrict__ twp, const float* __restrict__ tbp,
    const int* __restrict__ nidx, const float* __restrict__ nts,
    const float* __restrict__ ts, bf16* __restrict__ haw) {
  const int w = threadIdx.x >> 6, lane = threadIdx.x & 63;
  const int wid = __builtin_amdgcn_readfirstlane(blockIdx.x * 4 + w);
  const float t_now = ts[NED - 1];

  // neighbor meta: wave-uniform -> scalar loads
  int ixs[10]; float ndt[10];
  #pragma unroll
  for (int j = 0; j < 10; j++) ixs[j] = nidx[wid * 10 + j];
  #pragma unroll
  for (int j = 0; j < 10; j++) ndt[j] = t_now - nts[wid * 10 + j];

  const short* row = (const short*)Cq + (size_t)wid * 384;
  // q chunk pre-masked by head: qs0 = q * [e<86], qs1 = q * [86<=e<172]
  float qs0[8], qs1[8];
  {
    short8 qc8 = {0, 0, 0, 0, 0, 0, 0, 0};
    if (lane < 22) qc8 = *(const short8*)(row + 8 * lane);
    #pragma unroll
    for (int p = 0; p < 8; p++) {
      const int e = 8 * lane + p;
      const float v = bfs2f(qc8[p]);
      qs0[p] = (e < 86) ? v : 0.f;
      qs1[p] = (e >= 86 && e < 172) ? v : 0.f;
    }
  }
  const bool ln36 = (lane < 36);
  // qk2 coefs (cols 172..371); loads past col 371 are in-buffer (tail slack), masked
  const float k0a = bfs2f(row[172 + lane]);
  const float k0b = ln36 ? bfs2f(row[236 + lane]) : 0.f;
  const float k1a = bfs2f(row[272 + lane]);
  const float k1b = ln36 ? bfs2f(row[336 + lane]) : 0.f;
  const float twa = twp[lane],      tba = tbp[lane];
  const float twb = twp[64 + lane], tbb = tbp[64 + lane];

  // ---- phase 1: QK scores (kv gathered, not held)
  float s0[10], s1[10];
  #pragma unroll
  for (int j = 0; j < 10; j++) {
    const short8 c = *(const short8*)(kv + (size_t)ixs[j] * 512 + 8 * lane);
    const float tja = cos_rev(fmaf(ndt[j], twa, tba));
    const float tjb = cos_rev(fmaf(ndt[j], twb, tbb));  // lanes>=36: killed by k*b=0
    float p0 = tja * k0a + tjb * k0b;
    float p1 = tja * k1a + tjb * k1b;
    #pragma unroll
    for (int p = 0; p < 8; p++) {
      const float hvv = bfs2f(c[p]);
      p0 = fmaf(qs0[p], hvv, p0);
      p1 = fmaf(qs1[p], hvv, p1);
    }
    #pragma unroll
    for (int off = 32; off; off >>= 1) {
      p0 += __shfl_xor(p0, off);
      p1 += __shfl_xor(p1, off);
    }
    const float scale = 0.10783277320343841f;  // 1/sqrt(86)
    s0[j] = p0 * scale; s1[j] = p1 * scale;
  }
  // softmax per head (redundant per-lane, registers only)
  float m0 = s0[0], m1v = s1[0];
  #pragma unroll
  for (int j = 1; j < 10; j++) { m0 = fmaxf(m0, s0[j]); m1v = fmaxf(m1v, s1[j]); }
  float z0 = 0.f, z1 = 0.f;
  #pragma unroll
  for (int j = 0; j < 10; j++) {
    s0[j] = fast_exp(s0[j] - m0);  z0 += s0[j];
    s1[j] = fast_exp(s1[j] - m1v); z1 += s1[j];
  }
  const float i0 = fast_rcp(z0), i1 = fast_rcp(z1);

  // ---- phase 2: agg + wt (re-gather kv, recompute time enc)
  float av0[8] = {}, av1[8] = {};
  float w0a = 0.f, w0b = 0.f, w1a = 0.f, w1b = 0.f;
  #pragma unroll
  for (int j = 0; j < 10; j++) {
    const short8 c = *(const short8*)(kv + (size_t)ixs[j] * 512 + 8 * lane);
    const float tja = cos_rev(fmaf(ndt[j], twa, tba));
    const float tjb = cos_rev(fmaf(ndt[j], twb, tbb));
    const float a0 = s0[j] * i0, a1 = s1[j] * i1;
    #pragma unroll
    for (int p = 0; p < 8; p++) {
      const float hvv = bfs2f(c[p]);
      av0[p] = fmaf(a0, hvv, av0[p]);
      av1[p] = fmaf(a1, hvv, av1[p]);
    }
    w0a = fmaf(a0, tja, w0a); w0b = fmaf(a0, tjb, w0b);
    w1a = fmaf(a1, tja, w1a); w1b = fmaf(a1, tjb, w1b);
  }
  bf16* hrow = haw + (size_t)wid * 544;
  if (lane >= 22 && lane < 43) {        // aggv cols 8*lane .. 8*lane+7 (176..343)
    short8 st;
    #pragma unroll
    for (int p = 0; p < 8; p++) {
      const int e = 8 * lane + p;
      st[p] = f2bfs((e < 258) ? av0[p] : av1[p]);
    }
    *(short8*)(hrow + 8 * lane) = st;
  } else if (lane == 21) {              // aggv cols 172..175 (positions 4..7)
    #pragma unroll
    for (int p = 4; p < 8; p++) hrow[168 + p] = __float2bfloat16(av0[p]);
  }
  // wt: cols 344..543 = [head0 d0..99 | head1 d0..99]
  hrow[344 + lane] = __float2bfloat16(w0a);
  if (ln36) hrow[408 + lane] = __float2bfloat16(w0b);
  hrow[444 + lane] = __float2bfloat16(w1a);
  if (ln36) hrow[508 + lane] = __float2bfloat16(w1b);
}

// ---------------------------------------------------------------- classifier head

__global__ void head_k(const float* __restrict__ relu_sum, const float* __restrict__ W2,
                       const float* __restrict__ b2, const float* __restrict__ fc2w,
                       const float* __restrict__ fc2b, float* out) {
  __shared__ float th[172];
  int t = threadIdx.x;
  if (t < 172) {
    float s = 0.f;
    for (int c = 0; c < 172; c++) s = fmaf(relu_sum[c], W2[c * 172 + t], s);
    s = s * (1.0f / 99999.0f) + b2[t];
    th[t] = tanhf(s);
  }
  __syncthreads();
  if (t == 0) {
    float l0 = fc2b[0], l1 = fc2b[1];
    for (int o = 0; o < 172; o++) {
      l0 = fmaf(th[o], fc2w[o * 2 + 0], l0);
      l1 = fmaf(th[o], fc2w[o * 2 + 1], l1);
    }
    float mx = fmaxf(l0, l1);
    float e0 = expf(l0 - mx), e1 = expf(l1 - mx);
    float inv = 1.f / (e0 + e1);
    out[0] = e0 * inv;
    out[1] = e1 * inv;
  }
}

// ---------------------------------------------------------------- launch

extern "C" void kernel_launch(void* const* d_in, const int* in_sizes, int n_in,
                              void* d_out, int out_size, void* d_ws, size_t ws_size,
                              hipStream_t stream) {
  (void)in_sizes; (void)n_in; (void)out_size;
  const float* node_features = (const float*)d_in[0];
  const float* memory        = (const float*)d_in[1];
  const float* last_update   = (const float*)d_in[2];
  const float* timestamps    = (const float*)d_in[3];
  const float* edge_features = (const float*)d_in[4];
  const float* neighbor_ts   = (const float*)d_in[5];
  const float* time_w        = (const float*)d_in[6];
  const float* time_b        = (const float*)d_in[7];
  const float* gru_Wi        = (const float*)d_in[8];
  const float* gru_Wh        = (const float*)d_in[9];
  const float* gru_bi        = (const float*)d_in[10];
  const float* gru_bh        = (const float*)d_in[11];
  const float* Wq            = (const float*)d_in[12];
  const float* Wk            = (const float*)d_in[13];
  const float* Wv            = (const float*)d_in[14];
  const float* W1            = (const float*)d_in[15];
  const float* b1            = (const float*)d_in[16];
  const float* W2            = (const float*)d_in[17];
  const float* b2            = (const float*)d_in[18];
  const float* fc2_w         = (const float*)d_in[19];
  const float* fc2_b         = (const float*)d_in[20];
  const int* sources         = (const int*)d_in[21];
  const int* destinations    = (const int*)d_in[22];
  const int* neighbor_idx    = (const int*)d_in[23];
  float* out = (float*)d_out;

  float* F = (float*)d_ws;
  int*   I = (int*)d_ws;
  size_t off = 0;
  auto alloc = [&off](size_t words) { size_t r = off; off += (words + 63) & ~(size_t)63; return r; };
  const size_t w_lastpos = alloc(NND);
  const size_t w_other   = alloc(NND);
  const size_t w_edge    = alloc(NND);
  const size_t w_dtv     = alloc(NND);
  const size_t w_hasm    = alloc(NND);
  const size_t w_qbias   = alloc(172);
  const size_t w_b716    = alloc(716);
  const size_t w_relu    = alloc(172);
  const size_t w_twp     = alloc(128);
  const size_t w_tbp     = alloc(128);
  const size_t w_WiB     = alloc(640 * 640 / 2);
  const size_t w_WhB     = alloc(640 * 192 / 2);
  const size_t w_pBT     = alloc(768 * 192 / 2);
  const size_t w_W1x     = alloc(256 * 544 / 2);
  const size_t w_R1 = alloc((size_t)NND * 372 + 256);  // Mg bf16 -> ghB bf16 -> Cq bf16[384] (+slack)
  const size_t w_R2 = alloc((size_t)NND * 516 / 2);    // giB -> kvB (512-stride bf16)
  const size_t w_R4 = alloc((size_t)MROWS * 192 / 2);  // memB -> hB
  const size_t w_R5 = alloc((size_t)MROWS * 544 / 2);  // haw [h|aggv|wt]
  if (ws_size < off * 4) return;  // insufficient scratch -> visible failure

  int*   lastpos = I + w_lastpos;
  int*   other   = I + w_other;
  int*   edge    = I + w_edge;
  float* dtv     = F + w_dtv;
  int*   hasm    = I + w_hasm;
  float* qbias   = F + w_qbias;
  float* b716    = F + w_b716;
  float* relu_s  = F + w_relu;
  float* twp     = F + w_twp;
  float* tbp     = F + w_tbp;
  bf16*  WiB     = (bf16*)(F + w_WiB);
  bf16*  WhB     = (bf16*)(F + w_WhB);
  bf16*  pBT     = (bf16*)(F + w_pBT);
  bf16*  W1x     = (bf16*)(F + w_W1x);
  bf16*  Mg      = (bf16*)(F + w_R1);
  bf16*  ghB     = (bf16*)(F + w_R1);   // after Mg is dead
  bf16*  Cqb     = (bf16*)(F + w_R1);   // after ghB is dead; [NND x 384] bf16
  bf16*  giB     = (bf16*)(F + w_R2);
  bf16*  kvB     = (bf16*)(F + w_R2);   // after giB is dead; [NND x 512] bf16
  bf16*  memB    = (bf16*)(F + w_R4);
  bf16*  hB      = (bf16*)(F + w_R4);   // after memB is dead
  bf16*  haw     = (bf16*)(F + w_R5);

  init_k<<<(NND + 255) / 256, 256, 0, stream>>>(lastpos, relu_s, time_w, time_b, twp, tbp);
  scatter_k<<<(NED + 255) / 256, 256, 0, stream>>>(sources, destinations, lastpos);
  meta_k<<<(NND + 255) / 256, 256, 0, stream>>>(lastpos, sources, destinations,
                                                timestamps, last_update,
                                                other, edge, dtv, hasm);
  qbias_k<<<1, 256, 0, stream>>>(time_b, Wq, qbias);
  bias716_k<<<3, 256, 0, stream>>>(qbias, Wk, b716);
  cvtW_k<<<(640 * 640 + 255) / 256, 256, 0, stream>>>(gru_Wi, WiB, 640, 640, 516, 616);
  cvtW_k<<<(640 * 192 + 255) / 256, 256, 0, stream>>>(gru_Wh, WhB, 640, 192, 516, 172);
  packBT_k<<<(768 * 192 + 255) / 256, 256, 0, stream>>>(Wq, Wk, Wv, pBT);
  packW1x_k<<<(256 * 544 + 255) / 256, 256, 0, stream>>>(W1, Wv, W1x);
  msg2_k<<<(MROWS * 80) / 256, 256, 0, stream>>>(memory, edge_features, other, edge,
                                                 dtv, twp, tbp, Mg);
  cvtmem_k<<<(MROWS * 192) / 256, 256, 0, stream>>>(memory, memB);
  padrow_k<<<((MROWS - NND) * 544 + 255) / 256, 256, 0, stream>>>(haw);

  // gi = msg @ Wi^T + bi  -> bf16
  mgemm_k<2><<<dim3(5, 782), 256, 0, stream>>>(Mg, 640, WiB, 640, gru_bi,
                                               nullptr, 0, giB, 516, nullptr,
                                               NND, 516, 640);
  // gh = memory @ Wh^T + bh -> bf16 (into R1; Mg dead now)
  mgemm_k<2><<<dim3(5, 782), 256, 0, stream>>>(memB, 192, WhB, 192, gru_bh,
                                               nullptr, 0, ghB, 516, nullptr,
                                               NND, 516, 192);
  gru2_k<<<(MROWS * 48) / 256, 256, 0, stream>>>(giB, ghB, memory, node_features,
                                                 hasm, hB, haw);
  // [q|hk|hv|qk2] = h @ packB  (split epilogue: Cqb bf16 s384, kvB bf16 s512 + zero-pad)
  mgemm_k<3><<<dim3(6, 782), 256, 0, stream>>>(hB, 192, pBT, 192, b716,
                                               Cqb, 384, kvB, 512, nullptr,
                                               NND, 716, 192);
  attn5_k<<<NND / 4, 256, 0, stream>>>(Cqb, kvB, twp, tbp,
                                       neighbor_idx, neighbor_ts, timestamps, haw);
  // relu_sum += colsum(relu([h|aggv|wt] @ W1x + b1)), rows 1..N-1
  mgemm_k<1><<<dim3(2, 782), 256, 0, stream>>>(haw, 544, W1x, 544, b1,
                                               nullptr, 0, nullptr, 0, relu_s,
                                               NND, 172, 544);
  head_k<<<1, 256, 0, stream>>>(relu_s, W2, b2, fc2_w, fc2_b, out);
}

// Round 5
// 1441.731 us; speedup vs baseline: 2.4311x; 2.4311x over previous
//
#include <hip/hip_runtime.h>
#include <hip/hip_bf16.h>
#include <math.h>

#define NND 100000   // nodes
#define NED 200000   // edges
#define MROWS 100096 // NND padded to 128-multiple (782 M-tiles)
// MEM=172, TD=100, K=10, MSG=616, 3*MEM=516

using bf16 = __hip_bfloat16;
using short8 = __attribute__((ext_vector_type(8))) short;
using short4v = __attribute__((ext_vector_type(4))) short;
using f32x4  = __attribute__((ext_vector_type(4))) float;

typedef __attribute__((address_space(3))) void lds_t;
typedef __attribute__((address_space(1))) const void gv_t;
__device__ __forceinline__ void gl16(const void* g, void* l) {
  __builtin_amdgcn_global_load_lds((gv_t*)g, (lds_t*)l, 16, 0, 0);
}

__device__ __forceinline__ float bfs2f(short s) {
  union { unsigned u; float f; } v; v.u = ((unsigned)(unsigned short)s) << 16; return v.f;
}
__device__ __forceinline__ short f2bfs(float f) {
  bf16 b = __float2bfloat16(f);
  union { bf16 b; short s; } u; u.b = b; return u.s;
}

// ---- native-transcendental helpers (v_cos/v_exp/v_rcp; quarter-rate HW pipes)
#define INV2PI 0.15915494309189533577f

__device__ __forceinline__ float cos_rev(float r) {
  r = r - floorf(r);
  return __builtin_amdgcn_cosf(r);
}
__device__ __forceinline__ float fast_exp(float x) { return __expf(x); }
__device__ __forceinline__ float fast_rcp(float x) { return __builtin_amdgcn_rcpf(x); }
__device__ __forceinline__ float fast_sigmoid(float x) {
  return __builtin_amdgcn_rcpf(1.f + __expf(-x));
}
__device__ __forceinline__ float fast_tanh(float x) {
  float e = __expf(2.f * fabsf(x));
  float t = 1.f - 2.f * __builtin_amdgcn_rcpf(e + 1.f);
  return copysignf(t, x);
}

// ---------------------------------------------------------------- small kernels

__global__ void init_k(int* lastpos, float* relu_sum, const float* __restrict__ tw,
                       const float* __restrict__ tb, float* twp, float* tbp) {
  int i = blockIdx.x * 256 + threadIdx.x;
  if (i < NND) lastpos[i] = -1;
  if (i < 172) relu_sum[i] = 0.f;
  if (i < 128) {  // prescaled (revolutions) zero-padded time-encoding coeffs
    twp[i] = (i < 100) ? tw[i] * INV2PI : 0.f;
    tbp[i] = (i < 100) ? tb[i] * INV2PI : 0.f;
  }
}

__global__ void scatter_k(const int* __restrict__ src, const int* __restrict__ dst,
                          int* lastpos) {
  int e = blockIdx.x * 256 + threadIdx.x;
  if (e < NED) {
    atomicMax(&lastpos[src[e]], e);
    atomicMax(&lastpos[dst[e]], NED + e);
  }
}

__global__ void meta_k(const int* __restrict__ lastpos,
                       const int* __restrict__ src, const int* __restrict__ dst,
                       const float* __restrict__ ts, const float* __restrict__ last_update,
                       int* other, int* edge, float* dtv, int* hasm) {
  int n = blockIdx.x * 256 + threadIdx.x;
  if (n >= NND) return;
  int p = lastpos[n];
  int oth = n, e = 0, hm = 0;
  float d = 0.f;
  if (p >= 0) {
    hm = 1;
    if (p >= NED) { e = p - NED; oth = src[e]; }   // node was destination
    else          { e = p;       oth = dst[e]; }   // node was source
    d = ts[e] - last_update[n];
  }
  other[n] = oth; edge[n] = e; dtv[n] = d; hasm[n] = hm;
}

__global__ void qbias_k(const float* __restrict__ tb, const float* __restrict__ Wq,
                        float* qbias) {
  int o = threadIdx.x;
  if (o < 172) {
    float s = 0.f;
    for (int d = 0; d < 100; d++) s += cosf(tb[d]) * Wq[(172 + d) * 172 + o];
    qbias[o] = s;
  }
}

// bias for the 716 proj cols: [qbias | 0(344) | qk2-const]
__global__ void bias716_k(const float* __restrict__ qbias, const float* __restrict__ Wk,
                          float* bias) {
  int o = blockIdx.x * 256 + threadIdx.x;
  if (o >= 716) return;
  float v = 0.f;
  if (o < 172) v = qbias[o];
  else if (o >= 516) {
    int p = o - 516, hh = p / 100, d = p - hh * 100;
    const float* qb  = qbias + hh * 86;
    const float* wk2 = Wk + (172 + d) * 172 + hh * 86;
    float s = 0.f;
    for (int cc = 0; cc < 86; cc++) s = fmaf(qb[cc], wk2[cc], s);
    v = s;
  }
  bias[o] = v;
}

// f32 -> bf16 weight convert with zero padding
__global__ void cvtW_k(const float* __restrict__ src, bf16* __restrict__ dst,
                       int R, int S, int r, int s) {
  int i = blockIdx.x * 256 + threadIdx.x;
  if (i >= R * S) return;
  int rr = i / S, cc = i - rr * S;
  float v = (rr < r && cc < s) ? src[(size_t)rr * s + cc] : 0.f;
  dst[i] = __float2bfloat16(v);
}

// packed proj weight, transposed bf16: [768 rows x 192] = [Wq | Wk | Wv | Wqk2]^T
__global__ void packBT_k(const float* __restrict__ Wq, const float* __restrict__ Wk,
                         const float* __restrict__ Wv, bf16* __restrict__ dst) {
  int i = blockIdx.x * 256 + threadIdx.x;
  if (i >= 768 * 192) return;
  int o = i / 192, c = i - o * 192;
  float v = 0.f;
  if (o < 716 && c < 172) {
    if (o < 172)      v = Wq[c * 172 + o];
    else if (o < 344) v = Wk[c * 172 + (o - 172)];
    else if (o < 516) v = Wv[c * 172 + (o - 344)];
    else {
      int p = o - 516, hh = p / 100, d = p - hh * 100;
      const float* wq  = Wq + c * 172 + hh * 86;
      const float* wk2 = Wk + (172 + d) * 172 + hh * 86;
      float s = 0.f;
      for (int cc = 0; cc < 86; cc++) s = fmaf(wq[cc], wk2[cc], s);
      v = s;
    }
  }
  dst[i] = __float2bfloat16(v);
}

// extended W1 weight, transposed bf16: [256 rows x 544]
__global__ void packW1x_k(const float* __restrict__ W1, const float* __restrict__ Wv,
                          bf16* __restrict__ dst) {
  int i = blockIdx.x * 256 + threadIdx.x;
  if (i >= 256 * 544) return;
  int o = i / 544, k = i - o * 544;
  float v = 0.f;
  if (o < 172) {
    if (k < 344) v = W1[(size_t)k * 172 + o];
    else {
      int p = k - 344, hh = p / 100, d = p - hh * 100;
      const float* wv2 = Wv + (size_t)(172 + d) * 172;
      float s = 0.f;
      for (int t = hh * 86; t < hh * 86 + 86; t++)
        s = fmaf(wv2[t], W1[(size_t)(172 + t) * 172 + o], s);
      v = s;
    }
  }
  dst[i] = __float2bfloat16(v);
}

// message matrix Mg [MROWS x 640] bf16; one thread = one short8 (8 cols)
__global__ void msg2_k(const float* __restrict__ mem, const float* __restrict__ ef,
                       const int* __restrict__ other, const int* __restrict__ edge,
                       const float* __restrict__ dtv, const float* __restrict__ twp,
                       const float* __restrict__ tbp, bf16* __restrict__ Mg) {
  int i = blockIdx.x * 256 + threadIdx.x;
  if (i >= MROWS * 80) return;
  int n = i / 80, c8 = i - n * 80;
  int c = c8 * 8;
  short8 st = {0, 0, 0, 0, 0, 0, 0, 0};
  if (n < NND && c < 616) {
    float v[8];
    if (c + 8 <= 172) {                       // memory[n]
      float4 a = *(const float4*)(mem + (size_t)n * 172 + c);
      float4 b = *(const float4*)(mem + (size_t)n * 172 + c + 4);
      v[0]=a.x; v[1]=a.y; v[2]=a.z; v[3]=a.w; v[4]=b.x; v[5]=b.y; v[6]=b.z; v[7]=b.w;
    } else if (c >= 176 && c + 8 <= 344) {    // memory[other]
      const float* src = mem + (size_t)other[n] * 172 + (c - 172);
      float4 a = *(const float4*)(src);
      float4 b = *(const float4*)(src + 4);
      v[0]=a.x; v[1]=a.y; v[2]=a.z; v[3]=a.w; v[4]=b.x; v[5]=b.y; v[6]=b.z; v[7]=b.w;
    } else if (c >= 344 && c + 8 <= 516) {    // edge features
      const float* src = ef + (size_t)edge[n] * 172 + (c - 344);
      float4 a = *(const float4*)(src);
      float4 b = *(const float4*)(src + 4);
      v[0]=a.x; v[1]=a.y; v[2]=a.z; v[3]=a.w; v[4]=b.x; v[5]=b.y; v[6]=b.z; v[7]=b.w;
    } else if (c >= 520) {                    // pure time-encoding
      float d0 = dtv[n];
      #pragma unroll
      for (int p = 0; p < 8; p++)
        v[p] = cos_rev(fmaf(d0, twp[c - 516 + p], tbp[c - 516 + p]));
    } else {                                  // boundary threads (c8==21, c8==64)
      float d0 = dtv[n];
      #pragma unroll
      for (int p = 0; p < 8; p++) {
        int col = c + p;
        float x;
        if (col < 172)      x = mem[(size_t)n * 172 + col];
        else if (col < 344) x = mem[(size_t)other[n] * 172 + (col - 172)];
        else if (col < 516) x = ef[(size_t)edge[n] * 172 + (col - 344)];
        else                x = cos_rev(fmaf(d0, twp[col - 516], tbp[col - 516]));
        v[p] = x;
      }
    }
    #pragma unroll
    for (int p = 0; p < 8; p++) st[p] = f2bfs(v[p]);
  }
  *(short8*)(Mg + (size_t)n * 640 + c) = st;
}

// memory f32 -> bf16 [MROWS x 192] zero-padded
__global__ void cvtmem_k(const float* __restrict__ mem, bf16* __restrict__ dst) {
  int i = blockIdx.x * 256 + threadIdx.x;
  if (i >= MROWS * 192) return;
  int n = i / 192, c = i - n * 192;
  float v = (n < NND && c < 172) ? mem[(size_t)n * 172 + c] : 0.f;
  dst[i] = __float2bfloat16(v);
}

// zero pad rows of haw (rows NND..MROWS-1, 544 cols)
__global__ void padrow_k(bf16* __restrict__ haw) {
  int i = blockIdx.x * 256 + threadIdx.x;
  if (i < (MROWS - NND) * 544) haw[(size_t)NND * 544 + i] = __float2bfloat16(0.f);
}

// GRU combine; one thread = 4 cols. Writes hB [MROWS x 192] and haw cols 0..171
__global__ void gru2_k(const bf16* __restrict__ gi, const bf16* __restrict__ gh,
                       const float* __restrict__ memory, const float* __restrict__ nf,
                       const int* __restrict__ hasm,
                       bf16* __restrict__ hB, bf16* __restrict__ haw) {
  int i = blockIdx.x * 256 + threadIdx.x;
  if (i >= MROWS * 48) return;
  int n = i / 48, c = (i - n * 48) * 4;
  short4v z4 = {0, 0, 0, 0};
  if (n >= NND || c >= 172) {
    *(short4v*)(hB + (size_t)n * 192 + c) = z4;
    return;
  }
  float4 mv = *(const float4*)(memory + (size_t)n * 172 + c);
  float hv[4] = {mv.x, mv.y, mv.z, mv.w};
  if (hasm[n]) {
    const bf16* gin = gi + (size_t)n * 516 + c;
    const bf16* ghn = gh + (size_t)n * 516 + c;
    short4v g0 = *(const short4v*)(gin);
    short4v g1 = *(const short4v*)(gin + 172);
    short4v g2 = *(const short4v*)(gin + 344);
    short4v h0 = *(const short4v*)(ghn);
    short4v h1 = *(const short4v*)(ghn + 172);
    short4v h2 = *(const short4v*)(ghn + 344);
    #pragma unroll
    for (int p = 0; p < 4; p++) {
      float r  = fast_sigmoid(bfs2f(g0[p]) + bfs2f(h0[p]));
      float zz = fast_sigmoid(bfs2f(g1[p]) + bfs2f(h1[p]));
      float nn = fast_tanh(bfs2f(g2[p]) + r * bfs2f(h2[p]));
      hv[p] = (1.f - zz) * nn + zz * hv[p];
    }
  }
  float4 nfv = *(const float4*)(nf + (size_t)n * 172 + c);
  float nfa[4] = {nfv.x, nfv.y, nfv.z, nfv.w};
  short4v hb;
  #pragma unroll
  for (int p = 0; p < 4; p++) hb[p] = f2bfs(hv[p] + nfa[p]);
  *(short4v*)(hB + (size_t)n * 192 + c) = hb;
  *(short4v*)(haw + (size_t)n * 544 + c) = hb;
}

// ---------------------------------------------------------------- bf16 MFMA GEMM
// C[M,O] = A[M,K] @ B^T + bias. 128x128 tile, BK=32, 4 waves.
// 2-phase double-buffered staging: stage next K-tile BEFORE computing current.
// EPI 1: relu + column-sum (skip row 0) -> red.  EPI 2: bf16 store to Cb.
// EPI 3: proj split -> Cq bf16 [q | qk2 -> cols 172..371] stride CqS,
//        Cb bf16 [cols 172..515 -> 0..343, zeros to 344..511] stride CbS.

template<int EPI>
__global__ __launch_bounds__(256) void mgemm_k(
    const bf16* __restrict__ A, int AS, const bf16* __restrict__ B, int BS,
    const float* __restrict__ bias,
    bf16* __restrict__ Cq, int CqS, bf16* __restrict__ Cb, int CbS,
    float* __restrict__ red, int M, int O, int K) {
  __shared__ bf16 As[2][128 * 32];
  __shared__ bf16 Bs[2][128 * 32];
  const int tid = threadIdx.x, w = tid >> 6, lane = tid & 63;
  const int m0 = blockIdx.y * 128, o0 = blockIdx.x * 128;
  const int quad = lane >> 4, l16 = lane & 15;
  const int wm = (w & 1) * 64, wn = (w >> 1) * 64;
  const int wo = w * 1024;
  f32x4 acc[4][4] = {};
  const bf16* ga = A + (size_t)(m0 + w * 32 + (lane >> 2)) * AS + (lane & 3) * 8;
  const bf16* gb = B + (size_t)(o0 + w * 32 + (lane >> 2)) * BS + (lane & 3) * 8;
  // prologue: stage buffer 0
  gl16(ga, As[0] + wo);  gl16(ga + (size_t)16 * AS, As[0] + wo + 512);
  gl16(gb, Bs[0] + wo);  gl16(gb + (size_t)16 * BS, Bs[0] + wo + 512);
  ga += 32; gb += 32;
  __syncthreads();                       // vmcnt(0) drain + join
  const int nt = K >> 5;
  int cur = 0;
  for (int t = 0; t < nt; ++t) {
    if (t + 1 < nt) {                    // stage NEXT tile into other buffer
      gl16(ga, As[cur ^ 1] + wo);  gl16(ga + (size_t)16 * AS, As[cur ^ 1] + wo + 512);
      gl16(gb, Bs[cur ^ 1] + wo);  gl16(gb + (size_t)16 * BS, Bs[cur ^ 1] + wo + 512);
      ga += 32; gb += 32;
    }
    short8 af[4], bfm[4];
    #pragma unroll
    for (int i = 0; i < 4; i++)
      af[i] = *(const short8*)&As[cur][(wm + i * 16 + l16) * 32 + quad * 8];
    #pragma unroll
    for (int j = 0; j < 4; j++)
      bfm[j] = *(const short8*)&Bs[cur][(wn + j * 16 + l16) * 32 + quad * 8];
    #pragma unroll
    for (int i = 0; i < 4; i++)
      #pragma unroll
      for (int j = 0; j < 4; j++)
        acc[i][j] = __builtin_amdgcn_mfma_f32_16x16x32_bf16(af[i], bfm[j], acc[i][j], 0, 0, 0);
    __syncthreads();                     // drain next-stage + all waves done reading cur
    cur ^= 1;
  }
  if (EPI == 2) {
    #pragma unroll
    for (int i = 0; i < 4; i++)
      #pragma unroll
      for (int p = 0; p < 4; p++) {
        const int m = m0 + wm + i * 16 + quad * 4 + p;
        if (m < M) {
          #pragma unroll
          for (int j = 0; j < 4; j++) {
            const int o = o0 + wn + j * 16 + l16;
            if (o < O) Cb[(size_t)m * CbS + o] = __float2bfloat16(acc[i][j][p] + bias[o]);
          }
        }
      }
  } else if (EPI == 3) {
    #pragma unroll
    for (int i = 0; i < 4; i++)
      #pragma unroll
      for (int p = 0; p < 4; p++) {
        const int m = m0 + wm + i * 16 + quad * 4 + p;
        if (m < M) {
          #pragma unroll
          for (int j = 0; j < 4; j++) {
            const int o = o0 + wn + j * 16 + l16;
            if (o < O) {
              const float v = acc[i][j][p] + bias[o];
              if (o < 172)      Cq[(size_t)m * CqS + o] = __float2bfloat16(v);
              else if (o < 516) Cb[(size_t)m * CbS + (o - 172)] = __float2bfloat16(v);
              else {
                Cq[(size_t)m * CqS + (o - 344)] = __float2bfloat16(v);
                if (o < 684) Cb[(size_t)m * CbS + (o - 172)] = __float2bfloat16(0.f);
              }
            }
          }
        }
      }
  } else {  // EPI == 1: relu + colsum (rows 1..M-1)
    __shared__ float colsum[128];
    if (tid < 128) colsum[tid] = 0.f;
    __syncthreads();
    float part[4] = {0.f, 0.f, 0.f, 0.f};
    #pragma unroll
    for (int i = 0; i < 4; i++)
      #pragma unroll
      for (int p = 0; p < 4; p++) {
        const int m = m0 + wm + i * 16 + quad * 4 + p;
        const bool valid = (m < M) && (m != 0);
        if (valid) {
          #pragma unroll
          for (int j = 0; j < 4; j++) {
            const int o = o0 + wn + j * 16 + l16;
            if (o < O) part[j] += fmaxf(acc[i][j][p] + bias[o], 0.f);
          }
        }
      }
    #pragma unroll
    for (int j = 0; j < 4; j++) atomicAdd(&colsum[wn + j * 16 + l16], part[j]);
    __syncthreads();
    if (tid < 128) {
      const int o = o0 + tid;
      if (o < O) atomicAdd(&red[o], colsum[tid]);
    }
  }
}

// ---------------------------------------------------------------- attention v5b
// Wave per node, branchless, VGPR-slim (no held kv/ta arrays). NO min-waves
// force: round-4 showed (256,8) caps VGPR at 32 -> 9.7 GB scratch spill.
// Natural allocation ~64-72 VGPR gives 6-8 waves/SIMD without spilling.
__global__ __launch_bounds__(256) void attn5_k(
    const bf16* __restrict__ Cq, const bf16* __restrict__ kv,
    const float* __restrict__ twp, const float* __restrict__ tbp,
    const int* __restrict__ nidx, const float* __restrict__ nts,
    const float* __restrict__ ts, bf16* __restrict__ haw) {
  const int w = threadIdx.x >> 6, lane = threadIdx.x & 63;
  const int wid = __builtin_amdgcn_readfirstlane(blockIdx.x * 4 + w);
  const float t_now = ts[NED - 1];

  // neighbor meta: wave-uniform -> scalar loads
  int ixs[10]; float ndt[10];
  #pragma unroll
  for (int j = 0; j < 10; j++) ixs[j] = nidx[wid * 10 + j];
  #pragma unroll
  for (int j = 0; j < 10; j++) ndt[j] = t_now - nts[wid * 10 + j];

  const short* row = (const short*)Cq + (size_t)wid * 384;
  // q chunk pre-masked by head: qs0 = q * [e<86], qs1 = q * [86<=e<172]
  float qs0[8], qs1[8];
  {
    short8 qc8 = {0, 0, 0, 0, 0, 0, 0, 0};
    if (lane < 22) qc8 = *(const short8*)(row + 8 * lane);
    #pragma unroll
    for (int p = 0; p < 8; p++) {
      const int e = 8 * lane + p;
      const float v = bfs2f(qc8[p]);
      qs0[p] = (e < 86) ? v : 0.f;
      qs1[p] = (e >= 86 && e < 172) ? v : 0.f;
    }
  }
  const bool ln36 = (lane < 36);
  // qk2 coefs (cols 172..371); loads past col 371 are in-buffer (tail slack), masked
  const float k0a = bfs2f(row[172 + lane]);
  const float k0b = ln36 ? bfs2f(row[236 + lane]) : 0.f;
  const float k1a = bfs2f(row[272 + lane]);
  const float k1b = ln36 ? bfs2f(row[336 + lane]) : 0.f;
  const float twa = twp[lane],      tba = tbp[lane];
  const float twb = twp[64 + lane], tbb = tbp[64 + lane];

  // ---- phase 1: QK scores (kv gathered, not held)
  float s0[10], s1[10];
  #pragma unroll
  for (int j = 0; j < 10; j++) {
    const short8 c = *(const short8*)(kv + (size_t)ixs[j] * 512 + 8 * lane);
    const float tja = cos_rev(fmaf(ndt[j], twa, tba));
    const float tjb = cos_rev(fmaf(ndt[j], twb, tbb));  // lanes>=36: killed by k*b=0
    float p0 = tja * k0a + tjb * k0b;
    float p1 = tja * k1a + tjb * k1b;
    #pragma unroll
    for (int p = 0; p < 8; p++) {
      const float hvv = bfs2f(c[p]);
      p0 = fmaf(qs0[p], hvv, p0);
      p1 = fmaf(qs1[p], hvv, p1);
    }
    #pragma unroll
    for (int off = 32; off; off >>= 1) {
      p0 += __shfl_xor(p0, off);
      p1 += __shfl_xor(p1, off);
    }
    const float scale = 0.10783277320343841f;  // 1/sqrt(86)
    s0[j] = p0 * scale; s1[j] = p1 * scale;
  }
  // softmax per head (redundant per-lane, registers only)
  float m0 = s0[0], m1v = s1[0];
  #pragma unroll
  for (int j = 1; j < 10; j++) { m0 = fmaxf(m0, s0[j]); m1v = fmaxf(m1v, s1[j]); }
  float z0 = 0.f, z1 = 0.f;
  #pragma unroll
  for (int j = 0; j < 10; j++) {
    s0[j] = fast_exp(s0[j] - m0);  z0 += s0[j];
    s1[j] = fast_exp(s1[j] - m1v); z1 += s1[j];
  }
  const float i0 = fast_rcp(z0), i1 = fast_rcp(z1);

  // ---- phase 2: agg + wt (re-gather kv, recompute time enc)
  float av0[8] = {}, av1[8] = {};
  float w0a = 0.f, w0b = 0.f, w1a = 0.f, w1b = 0.f;
  #pragma unroll
  for (int j = 0; j < 10; j++) {
    const short8 c = *(const short8*)(kv + (size_t)ixs[j] * 512 + 8 * lane);
    const float tja = cos_rev(fmaf(ndt[j], twa, tba));
    const float tjb = cos_rev(fmaf(ndt[j], twb, tbb));
    const float a0 = s0[j] * i0, a1 = s1[j] * i1;
    #pragma unroll
    for (int p = 0; p < 8; p++) {
      const float hvv = bfs2f(c[p]);
      av0[p] = fmaf(a0, hvv, av0[p]);
      av1[p] = fmaf(a1, hvv, av1[p]);
    }
    w0a = fmaf(a0, tja, w0a); w0b = fmaf(a0, tjb, w0b);
    w1a = fmaf(a1, tja, w1a); w1b = fmaf(a1, tjb, w1b);
  }
  bf16* hrow = haw + (size_t)wid * 544;
  if (lane >= 22 && lane < 43) {        // aggv cols 8*lane .. 8*lane+7 (176..343)
    short8 st;
    #pragma unroll
    for (int p = 0; p < 8; p++) {
      const int e = 8 * lane + p;
      st[p] = f2bfs((e < 258) ? av0[p] : av1[p]);
    }
    *(short8*)(hrow + 8 * lane) = st;
  } else if (lane == 21) {              // aggv cols 172..175 (positions 4..7)
    #pragma unroll
    for (int p = 4; p < 8; p++) hrow[168 + p] = __float2bfloat16(av0[p]);
  }
  // wt: cols 344..543 = [head0 d0..99 | head1 d0..99]
  hrow[344 + lane] = __float2bfloat16(w0a);
  if (ln36) hrow[408 + lane] = __float2bfloat16(w0b);
  hrow[444 + lane] = __float2bfloat16(w1a);
  if (ln36) hrow[508 + lane] = __float2bfloat16(w1b);
}

// ---------------------------------------------------------------- classifier head

__global__ void head_k(const float* __restrict__ relu_sum, const float* __restrict__ W2,
                       const float* __restrict__ b2, const float* __restrict__ fc2w,
                       const float* __restrict__ fc2b, float* out) {
  __shared__ float th[172];
  int t = threadIdx.x;
  if (t < 172) {
    float s = 0.f;
    for (int c = 0; c < 172; c++) s = fmaf(relu_sum[c], W2[c * 172 + t], s);
    s = s * (1.0f / 99999.0f) + b2[t];
    th[t] = tanhf(s);
  }
  __syncthreads();
  if (t == 0) {
    float l0 = fc2b[0], l1 = fc2b[1];
    for (int o = 0; o < 172; o++) {
      l0 = fmaf(th[o], fc2w[o * 2 + 0], l0);
      l1 = fmaf(th[o], fc2w[o * 2 + 1], l1);
    }
    float mx = fmaxf(l0, l1);
    float e0 = expf(l0 - mx), e1 = expf(l1 - mx);
    float inv = 1.f / (e0 + e1);
    out[0] = e0 * inv;
    out[1] = e1 * inv;
  }
}

// ---------------------------------------------------------------- launch

extern "C" void kernel_launch(void* const* d_in, const int* in_sizes, int n_in,
                              void* d_out, int out_size, void* d_ws, size_t ws_size,
                              hipStream_t stream) {
  (void)in_sizes; (void)n_in; (void)out_size;
  const float* node_features = (const float*)d_in[0];
  const float* memory        = (const float*)d_in[1];
  const float* last_update   = (const float*)d_in[2];
  const float* timestamps    = (const float*)d_in[3];
  const float* edge_features = (const float*)d_in[4];
  const float* neighbor_ts   = (const float*)d_in[5];
  const float* time_w        = (const float*)d_in[6];
  const float* time_b        = (const float*)d_in[7];
  const float* gru_Wi        = (const float*)d_in[8];
  const float* gru_Wh        = (const float*)d_in[9];
  const float* gru_bi        = (const float*)d_in[10];
  const float* gru_bh        = (const float*)d_in[11];
  const float* Wq            = (const float*)d_in[12];
  const float* Wk            = (const float*)d_in[13];
  const float* Wv            = (const float*)d_in[14];
  const float* W1            = (const float*)d_in[15];
  const float* b1            = (const float*)d_in[16];
  const float* W2            = (const float*)d_in[17];
  const float* b2            = (const float*)d_in[18];
  const float* fc2_w         = (const float*)d_in[19];
  const float* fc2_b         = (const float*)d_in[20];
  const int* sources         = (const int*)d_in[21];
  const int* destinations    = (const int*)d_in[22];
  const int* neighbor_idx    = (const int*)d_in[23];
  float* out = (float*)d_out;

  float* F = (float*)d_ws;
  int*   I = (int*)d_ws;
  size_t off = 0;
  auto alloc = [&off](size_t words) { size_t r = off; off += (words + 63) & ~(size_t)63; return r; };
  const size_t w_lastpos = alloc(NND);
  const size_t w_other   = alloc(NND);
  const size_t w_edge    = alloc(NND);
  const size_t w_dtv     = alloc(NND);
  const size_t w_hasm    = alloc(NND);
  const size_t w_qbias   = alloc(172);
  const size_t w_b716    = alloc(716);
  const size_t w_relu    = alloc(172);
  const size_t w_twp     = alloc(128);
  const size_t w_tbp     = alloc(128);
  const size_t w_WiB     = alloc(640 * 640 / 2);
  const size_t w_WhB     = alloc(640 * 192 / 2);
  const size_t w_pBT     = alloc(768 * 192 / 2);
  const size_t w_W1x     = alloc(256 * 544 / 2);
  const size_t w_R1 = alloc((size_t)NND * 372 + 256);  // Mg bf16 -> ghB bf16 -> Cq bf16[384] (+slack)
  const size_t w_R2 = alloc((size_t)NND * 516 / 2);    // giB -> kvB (512-stride bf16)
  const size_t w_R4 = alloc((size_t)MROWS * 192 / 2);  // memB -> hB
  const size_t w_R5 = alloc((size_t)MROWS * 544 / 2);  // haw [h|aggv|wt]
  if (ws_size < off * 4) return;  // insufficient scratch -> visible failure

  int*   lastpos = I + w_lastpos;
  int*   other   = I + w_other;
  int*   edge    = I + w_edge;
  float* dtv     = F + w_dtv;
  int*   hasm    = I + w_hasm;
  float* qbias   = F + w_qbias;
  float* b716    = F + w_b716;
  float* relu_s  = F + w_relu;
  float* twp     = F + w_twp;
  float* tbp     = F + w_tbp;
  bf16*  WiB     = (bf16*)(F + w_WiB);
  bf16*  WhB     = (bf16*)(F + w_WhB);
  bf16*  pBT     = (bf16*)(F + w_pBT);
  bf16*  W1x     = (bf16*)(F + w_W1x);
  bf16*  Mg      = (bf16*)(F + w_R1);
  bf16*  ghB     = (bf16*)(F + w_R1);   // after Mg is dead
  bf16*  Cqb     = (bf16*)(F + w_R1);   // after ghB is dead; [NND x 384] bf16
  bf16*  giB     = (bf16*)(F + w_R2);
  bf16*  kvB     = (bf16*)(F + w_R2);   // after giB is dead; [NND x 512] bf16
  bf16*  memB    = (bf16*)(F + w_R4);
  bf16*  hB      = (bf16*)(F + w_R4);   // after memB is dead
  bf16*  haw     = (bf16*)(F + w_R5);

  init_k<<<(NND + 255) / 256, 256, 0, stream>>>(lastpos, relu_s, time_w, time_b, twp, tbp);
  scatter_k<<<(NED + 255) / 256, 256, 0, stream>>>(sources, destinations, lastpos);
  meta_k<<<(NND + 255) / 256, 256, 0, stream>>>(lastpos, sources, destinations,
                                                timestamps, last_update,
                                                other, edge, dtv, hasm);
  qbias_k<<<1, 256, 0, stream>>>(time_b, Wq, qbias);
  bias716_k<<<3, 256, 0, stream>>>(qbias, Wk, b716);
  cvtW_k<<<(640 * 640 + 255) / 256, 256, 0, stream>>>(gru_Wi, WiB, 640, 640, 516, 616);
  cvtW_k<<<(640 * 192 + 255) / 256, 256, 0, stream>>>(gru_Wh, WhB, 640, 192, 516, 172);
  packBT_k<<<(768 * 192 + 255) / 256, 256, 0, stream>>>(Wq, Wk, Wv, pBT);
  packW1x_k<<<(256 * 544 + 255) / 256, 256, 0, stream>>>(W1, Wv, W1x);
  msg2_k<<<(MROWS * 80) / 256, 256, 0, stream>>>(memory, edge_features, other, edge,
                                                 dtv, twp, tbp, Mg);
  cvtmem_k<<<(MROWS * 192) / 256, 256, 0, stream>>>(memory, memB);
  padrow_k<<<((MROWS - NND) * 544 + 255) / 256, 256, 0, stream>>>(haw);

  // gi = msg @ Wi^T + bi  -> bf16
  mgemm_k<2><<<dim3(5, 782), 256, 0, stream>>>(Mg, 640, WiB, 640, gru_bi,
                                               nullptr, 0, giB, 516, nullptr,
                                               NND, 516, 640);
  // gh = memory @ Wh^T + bh -> bf16 (into R1; Mg dead now)
  mgemm_k<2><<<dim3(5, 782), 256, 0, stream>>>(memB, 192, WhB, 192, gru_bh,
                                               nullptr, 0, ghB, 516, nullptr,
                                               NND, 516, 192);
  gru2_k<<<(MROWS * 48) / 256, 256, 0, stream>>>(giB, ghB, memory, node_features,
                                                 hasm, hB, haw);
  // [q|hk|hv|qk2] = h @ packB  (split epilogue: Cqb bf16 s384, kvB bf16 s512 + zero-pad)
  mgemm_k<3><<<dim3(6, 782), 256, 0, stream>>>(hB, 192, pBT, 192, b716,
                                               Cqb, 384, kvB, 512, nullptr,
                                               NND, 716, 192);
  attn5_k<<<NND / 4, 256, 0, stream>>>(Cqb, kvB, twp, tbp,
                                       neighbor_idx, neighbor_ts, timestamps, haw);
  // relu_sum += colsum(relu([h|aggv|wt] @ W1x + b1)), rows 1..N-1
  mgemm_k<1><<<dim3(2, 782), 256, 0, stream>>>(haw, 544, W1x, 544, b1,
                                               nullptr, 0, nullptr, 0, relu_s,
                                               NND, 172, 544);
  head_k<<<1, 256, 0, stream>>>(relu_s, W2, b2, fc2_w, fc2_b, out);
}